// Round 4
// baseline (491.393 us; speedup 1.0000x reference)
//
#include <hip/hip_runtime.h>
#include <hip/hip_bf16.h>
#include <cmath>

#define BB 8
#define PP 16384
#define CC 256
#define NCLUS 8
#define BPROWS (BB*PP)

typedef unsigned int uint;
typedef unsigned short ushort;
typedef __bf16 bf16x8 __attribute__((ext_vector_type(8)));
typedef float f32x16 __attribute__((ext_vector_type(16)));

__device__ __forceinline__ float bflo(uint u){ return __uint_as_float(u << 16); }
__device__ __forceinline__ float bfhi(uint u){ return __uint_as_float(u & 0xffff0000u); }
__device__ __forceinline__ ushort f2bf(float x){ __hip_bfloat16 h = __float2bfloat16(x); return *(ushort*)&h; }
__device__ __forceinline__ uint pk2(float a, float b){ return (uint)f2bf(a) | ((uint)f2bf(b) << 16); }

// D = A @ W^T + bias.  A: 131072 x 256 (fp32 if !ABF16, bf16 if ABF16), W: 256x256 fp32 (cvt to bf16).
// PROJ: D written bf16 + per-row rnorm.  !PROJ: D written fp32.
template<bool ABF16, bool PROJ>
__global__ __launch_bounds__(512) void gemm_mfma(const void* __restrict__ Av,
    const float* __restrict__ W, const float* __restrict__ bias,
    void* __restrict__ Dv, float* __restrict__ rnorm) {
  __shared__ __align__(16) char AlB[128*64*2];   // 16 KB, swizzled bf16 A tile
  __shared__ __align__(16) char WlB[256*64*2];   // 32 KB, swizzled bf16 W tile
  __shared__ float rnp[128][4];
  const int t  = threadIdx.x;
  const int p0 = blockIdx.x * 128;
  const int lane = t & 63;
  const int w  = t >> 6;
  const int wr = w >> 2, wc = w & 3;

  int aoff[2]; size_t agb[2];
  #pragma unroll
  for (int i = 0; i < 2; ++i) {
    int c = t + i*512, row = c >> 3, cc = c & 7;
    aoff[i] = row*128 + ((cc*16) ^ ((row & 7) << 4));
    agb[i]  = (size_t)(p0 + row)*CC + cc*8;
  }
  int woff[4]; size_t wgb[4];
  #pragma unroll
  for (int i = 0; i < 4; ++i) {
    int c = t + i*512, row = c >> 3, cc = c & 7;
    woff[i] = row*128 + ((cc*16) ^ ((row & 7) << 4));
    wgb[i]  = (size_t)row*CC + cc*8;
  }
  const int arow = (wr << 6) + (lane & 31);
  const int brow = (wc << 6) + (lane & 31);
  const int kb0  = (lane >> 5) << 4;

  uint4 ra[2], rw[4];
  auto LOADA = [&](int ks) {
    #pragma unroll
    for (int i = 0; i < 2; ++i) {
      if constexpr (ABF16) {
        ra[i] = *(const uint4*)((const ushort*)Av + agb[i] + ks*64);
      } else {
        const float* A = (const float*)Av;
        float4 v0 = *(const float4*)(A + agb[i] + ks*64);
        float4 v1 = *(const float4*)(A + agb[i] + ks*64 + 4);
        ra[i] = make_uint4(pk2(v0.x,v0.y), pk2(v0.z,v0.w), pk2(v1.x,v1.y), pk2(v1.z,v1.w));
      }
    }
  };
  auto LOADW = [&](int ks) {
    #pragma unroll
    for (int i = 0; i < 4; ++i) {
      float4 v0 = *(const float4*)(W + wgb[i] + ks*64);
      float4 v1 = *(const float4*)(W + wgb[i] + ks*64 + 4);
      rw[i] = make_uint4(pk2(v0.x,v0.y), pk2(v0.z,v0.w), pk2(v1.x,v1.y), pk2(v1.z,v1.w));
    }
  };
  auto WRITE = [&]() {
    #pragma unroll
    for (int i = 0; i < 2; ++i) *(uint4*)(AlB + aoff[i]) = ra[i];
    #pragma unroll
    for (int i = 0; i < 4; ++i) *(uint4*)(WlB + woff[i]) = rw[i];
  };

  f32x16 acc[2][2];
  #pragma unroll
  for (int fm = 0; fm < 2; ++fm)
    #pragma unroll
    for (int fn = 0; fn < 2; ++fn)
      #pragma unroll
      for (int r = 0; r < 16; ++r) acc[fm][fn][r] = 0.0f;

  LOADA(0); LOADW(0);
  WRITE();
  __syncthreads();

  #pragma unroll
  for (int ks = 0; ks < 4; ++ks) {
    if (ks < 3) { LOADA(ks+1); LOADW(ks+1); }
    bf16x8 af[2][4], bg[2][4];
    #pragma unroll
    for (int fm = 0; fm < 2; ++fm)
      #pragma unroll
      for (int kq = 0; kq < 4; ++kq) {
        int row = arow + (fm << 5);
        int off = row*128 + (((kq << 5) + kb0) ^ ((row & 7) << 4));
        af[fm][kq] = *(const bf16x8*)(AlB + off);
      }
    #pragma unroll
    for (int fn = 0; fn < 2; ++fn)
      #pragma unroll
      for (int kq = 0; kq < 4; ++kq) {
        int row = brow + (fn << 5);
        int off = row*128 + (((kq << 5) + kb0) ^ ((row & 7) << 4));
        bg[fn][kq] = *(const bf16x8*)(WlB + off);
      }
    #pragma unroll
    for (int kq = 0; kq < 4; ++kq)
      #pragma unroll
      for (int fm = 0; fm < 2; ++fm)
        #pragma unroll
        for (int fn = 0; fn < 2; ++fn)
          acc[fm][fn] = __builtin_amdgcn_mfma_f32_32x32x16_bf16(
              af[fm][kq], bg[fn][kq], acc[fm][fn], 0, 0, 0);
    __syncthreads();
    if (ks < 3) { WRITE(); __syncthreads(); }
  }

  const int colb = (wc << 6) + (lane & 31);
  const float b0 = bias[colb], b1 = bias[colb + 32];
  #pragma unroll
  for (int fm = 0; fm < 2; ++fm) {
    float rs[16];
    #pragma unroll
    for (int r = 0; r < 16; ++r) {
      int rowin = (r & 3) + ((r >> 2) << 3) + ((lane >> 5) << 2);
      size_t grow = (size_t)(p0 + (wr << 6) + (fm << 5) + rowin);
      float v0 = acc[fm][0][r] + b0;
      float v1 = acc[fm][1][r] + b1;
      if constexpr (PROJ) {
        ushort* D = (ushort*)Dv;
        D[grow*CC + colb]      = f2bf(v0);
        D[grow*CC + colb + 32] = f2bf(v1);
        rs[r] = v0*v0 + v1*v1;
      } else {
        float* D = (float*)Dv;
        D[grow*CC + colb]      = v0;
        D[grow*CC + colb + 32] = v1;
      }
    }
    if constexpr (PROJ) {
      #pragma unroll
      for (int m = 1; m < 32; m <<= 1)
        #pragma unroll
        for (int r = 0; r < 16; ++r) rs[r] += __shfl_xor(rs[r], m);
      if ((lane & 31) == 0) {
        #pragma unroll
        for (int r = 0; r < 16; ++r) {
          int rowin = (r & 3) + ((r >> 2) << 3) + ((lane >> 5) << 2);
          rnp[(wr << 6) + (fm << 5) + rowin][wc] = rs[r];
        }
      }
    }
  }
  if constexpr (PROJ) {
    __syncthreads();
    if (t < 128) {
      float s = rnp[t][0] + rnp[t][1] + rnp[t][2] + rnp[t][3];
      rnorm[p0 + t] = 1.0f / fmaxf(sqrtf(s), 1e-12f);
    }
  }
}

__global__ void init_centers(const ushort* __restrict__ nbf, float* __restrict__ centers) {
  const int idx[8] = {0, 2340, 4680, 7021, 9361, 11702, 14042, 16383};
  int b = blockIdx.x >> 3, k = blockIdx.x & 7;
  int c = threadIdx.x;
  centers[(size_t)(b*NCLUS + k)*CC + c] =
      __uint_as_float(((uint)nbf[((size_t)b*PP + idx[k])*CC + c]) << 16);
}

__global__ __launch_bounds__(256) void center_norm_init(const float* __restrict__ centers,
    float* __restrict__ cnorm, float* __restrict__ accs, float* __restrict__ counts) {
  const int row = blockIdx.x;
  const int t = threadIdx.x;
  float c = centers[(size_t)row*CC + t];
  float s2 = c*c;
  #pragma unroll
  for (int o = 32; o; o >>= 1) s2 += __shfl_xor(s2, o);
  __shared__ float ps[4];
  if ((t & 63) == 0) ps[t >> 6] = s2;
  __syncthreads();
  float tot = ps[0] + ps[1] + ps[2] + ps[3];
  cnorm[(size_t)row*CC + t] = c * (1.0f / fmaxf(sqrtf(tot), 1e-12f));
  #pragma unroll
  for (int s = 0; s < 8; ++s) accs[((size_t)s*64 + row)*CC + t] = 0.0f;
  if (t == 0) counts[row] = 0.0f;
}

// 4 threads per point: quarter-row dot partials + 2-step shuffle combine.
// Chunk rotation (j+q4)&7 keeps the 4 quarters on distinct LDS bank groups
// while global reads stay inside each lane's own 128B line.
__device__ __forceinline__ void sims4(const ushort* __restrict__ nrow, int q4,
                                      const float (*cnL)[CC], float* sims) {
  #pragma unroll
  for (int k = 0; k < 8; ++k) sims[k] = 0.0f;
  #pragma unroll
  for (int j = 0; j < 8; ++j) {
    const int ch  = (j + q4) & 7;
    const int col = q4*64 + ch*8;
    uint4 u = *(const uint4*)(nrow + col);
    float v0 = bflo(u.x), v1 = bfhi(u.x), v2 = bflo(u.y), v3 = bfhi(u.y);
    float v4 = bflo(u.z), v5 = bfhi(u.z), v6 = bflo(u.w), v7 = bfhi(u.w);
    #pragma unroll
    for (int k = 0; k < 8; ++k) {
      const float4* c = (const float4*)&cnL[k][col];
      float4 c0 = c[0], c1 = c[1];
      sims[k] += v0*c0.x + v1*c0.y + v2*c0.z + v3*c0.w
               + v4*c1.x + v5*c1.y + v6*c1.z + v7*c1.w;
    }
  }
  #pragma unroll
  for (int k = 0; k < 8; ++k) {
    sims[k] += __shfl_xor(sims[k], 1);
    sims[k] += __shfl_xor(sims[k], 2);
  }
}

// 64 points/block, 2048 blocks. Phase1: 4 threads/point argmax.
// Phase2: one column per thread over 64 points (L1-hot), direct global atomics.
__global__ __launch_bounds__(256) void assign_acc3(const ushort* __restrict__ nbf,
    const float* __restrict__ cnorm, float* __restrict__ accs, float* __restrict__ counts) {
  __shared__ float cnL[NCLUS][CC];
  __shared__ int assignL[64];
  __shared__ int cntL[NCLUS];
  const int t = threadIdx.x;
  const int b = blockIdx.x >> 8;            // 256 blocks per batch
  for (int i = t; i < NCLUS*CC; i += 256)
    ((float*)cnL)[i] = cnorm[(size_t)b*NCLUS*CC + i];
  if (t < NCLUS) cntL[t] = 0;
  __syncthreads();
  const int sub = t >> 2, q4 = t & 3;
  const size_t p = (size_t)blockIdx.x*64 + sub;
  float sims[8];
  sims4(nbf + p*CC, q4, cnL, sims);
  if (q4 == 0) {
    int best = 0; float bs = sims[0];
    #pragma unroll
    for (int k = 1; k < 8; ++k) if (sims[k] > bs) { bs = sims[k]; best = k; }
    assignL[sub] = best;
    atomicAdd(&cntL[best], 1);
  }
  __syncthreads();
  // phase 2: column c = t
  float a[8] = {0,0,0,0,0,0,0,0};
  const ushort* base = nbf + (size_t)blockIdx.x*64*CC;
  #pragma unroll 4
  for (int i = 0; i < 64; ++i) {
    int asg = __builtin_amdgcn_readfirstlane(assignL[i]);  // loop-uniform
    float v = __uint_as_float(((uint)base[(size_t)i*CC + t]) << 16);
    if      (asg == 0) a[0] += v;
    else if (asg == 1) a[1] += v;
    else if (asg == 2) a[2] += v;
    else if (asg == 3) a[3] += v;
    else if (asg == 4) a[4] += v;
    else if (asg == 5) a[5] += v;
    else if (asg == 6) a[6] += v;
    else               a[7] += v;
  }
  const int slot = blockIdx.x & 7;
  float* dst = accs + ((size_t)slot*BB + b)*NCLUS*CC;
  #pragma unroll
  for (int k = 0; k < 8; ++k) atomicAdd(&dst[k*CC + t], a[k]);
  if (t < NCLUS) atomicAdd(&counts[b*NCLUS + t], (float)cntL[t]);
}

__global__ __launch_bounds__(256) void centers_finalize(float* __restrict__ accs,
    float* __restrict__ counts, float* __restrict__ centers, float* __restrict__ cnorm) {
  const int row = blockIdx.x;
  const int t = threadIdx.x;
  float v = 0.0f;
  #pragma unroll
  for (int s = 0; s < 8; ++s) {
    v += accs[((size_t)s*64 + row)*CC + t];
    accs[((size_t)s*64 + row)*CC + t] = 0.0f;
  }
  float cnt = fmaxf(counts[row], 1.0f);
  float c = v / cnt;
  centers[(size_t)row*CC + t] = c;
  float s2 = c*c;
  #pragma unroll
  for (int o = 32; o; o >>= 1) s2 += __shfl_xor(s2, o);
  __shared__ float ps[4];
  if ((t & 63) == 0) ps[t >> 6] = s2;
  __syncthreads();
  float tot = ps[0] + ps[1] + ps[2] + ps[3];
  cnorm[(size_t)row*CC + t] = c * (1.0f / fmaxf(sqrtf(tot), 1e-12f));
  if (t == 0) counts[row] = 0.0f;
}

// 64 points/block, 2048 blocks, 4 threads/point.
__global__ __launch_bounds__(256) void final_fuse3(const ushort* __restrict__ nbf,
    const float* __restrict__ F_p, const float* __restrict__ cnorm,
    const float* __restrict__ centers, const float* __restrict__ rnorm,
    ushort* __restrict__ tbf) {
  __shared__ float cnL[NCLUS][CC];
  __shared__ float ceL[NCLUS][CC];
  const int t = threadIdx.x;
  const int b = blockIdx.x >> 8;
  for (int i = t; i < NCLUS*CC; i += 256) {
    ((float*)cnL)[i] = cnorm[(size_t)b*NCLUS*CC + i];
    ((float*)ceL)[i] = centers[(size_t)b*NCLUS*CC + i];
  }
  __syncthreads();
  const int sub = t >> 2, q4 = t & 3;
  const size_t p = (size_t)blockIdx.x*64 + sub;
  float sims[8];
  sims4(nbf + p*CC, q4, cnL, sims);
  float rn10 = rnorm[p] * 10.0f;
  float m = -1e30f;
  #pragma unroll
  for (int k = 0; k < 8; ++k) { sims[k] *= rn10; m = fmaxf(m, sims[k]); }
  float w[8], sw = 0.0f;
  #pragma unroll
  for (int k = 0; k < 8; ++k) { w[k] = __expf(sims[k] - m); sw += w[k]; }
  float inv = 1.0f / sw;
  #pragma unroll
  for (int k = 0; k < 8; ++k) w[k] *= inv;
  const float* fp = F_p + p*CC + q4*64;
  ushort* op = tbf + p*CC + q4*64;
  #pragma unroll
  for (int j = 0; j < 8; ++j) {
    const int ch  = (j + q4) & 7;       // rotated: conflict-free ceL, same lines
    float4 f0 = *(const float4*)&fp[ch*8];
    float4 f1 = *(const float4*)&fp[ch*8 + 4];
    #pragma unroll
    for (int k = 0; k < 8; ++k) {
      const float4* c = (const float4*)&ceL[k][q4*64 + ch*8];
      float4 c0 = c[0], c1 = c[1];
      f0.x = fmaf(w[k], c0.x, f0.x); f0.y = fmaf(w[k], c0.y, f0.y);
      f0.z = fmaf(w[k], c0.z, f0.z); f0.w = fmaf(w[k], c0.w, f0.w);
      f1.x = fmaf(w[k], c1.x, f1.x); f1.y = fmaf(w[k], c1.y, f1.y);
      f1.z = fmaf(w[k], c1.z, f1.z); f1.w = fmaf(w[k], c1.w, f1.w);
    }
    uint4 o;
    o.x = pk2(f0.x, f0.y);
    o.y = pk2(f0.z, f0.w);
    o.z = pk2(f1.x, f1.y);
    o.w = pk2(f1.z, f1.w);
    *(uint4*)&op[ch*8] = o;
  }
}

extern "C" void kernel_launch(void* const* d_in, const int* in_sizes, int n_in,
                              void* d_out, int out_size, void* d_ws, size_t ws_size,
                              hipStream_t stream) {
  const float* F_p      = (const float*)d_in[0];
  const float* proj_w   = (const float*)d_in[1];
  const float* proj_b   = (const float*)d_in[2];
  const float* refine_w = (const float*)d_in[3];
  const float* refine_b = (const float*)d_in[4];
  float* out = (float*)d_out;

  char* ws = (char*)d_ws;
  ushort* nbf    = (ushort*)ws;                                    // 64 MiB
  ushort* tbf    = (ushort*)(ws + (size_t)BPROWS*CC*2);            // 64 MiB
  float*  rnorm  = (float*)(ws + (size_t)BPROWS*CC*4);             // 512 KiB
  float*  centers= rnorm + BPROWS;
  float*  cnorm  = centers + BB*NCLUS*CC;
  float*  accs   = cnorm + BB*NCLUS*CC;                            // 8 slots
  float*  counts = accs + 8*BB*NCLUS*CC;

  gemm_mfma<false, true><<<1024, 512, 0, stream>>>(F_p, proj_w, proj_b, nbf, rnorm);
  init_centers<<<64, 256, 0, stream>>>(nbf, centers);
  center_norm_init<<<64, 256, 0, stream>>>(centers, cnorm, accs, counts);
  for (int it = 0; it < 3; ++it) {
    assign_acc3<<<2048, 256, 0, stream>>>(nbf, cnorm, accs, counts);
    centers_finalize<<<64, 256, 0, stream>>>(accs, counts, centers, cnorm);
  }
  final_fuse3<<<2048, 256, 0, stream>>>(nbf, F_p, cnorm, centers, rnorm, tbf);
  gemm_mfma<true, false><<<1024, 512, 0, stream>>>(tbf, refine_w, refine_b, out, nullptr);
}

// Round 5
// 368.830 us; speedup vs baseline: 1.3323x; 1.3323x over previous
//
#include <hip/hip_runtime.h>
#include <hip/hip_bf16.h>
#include <cmath>

#define BB 8
#define PP 16384
#define CC 256
#define NCLUS 8
#define BPROWS (BB*PP)

typedef unsigned int uint;
typedef unsigned short ushort;
typedef __bf16 bf16x8 __attribute__((ext_vector_type(8)));
typedef float f32x16 __attribute__((ext_vector_type(16)));

__device__ __forceinline__ float bflo(uint u){ return __uint_as_float(u << 16); }
__device__ __forceinline__ float bfhi(uint u){ return __uint_as_float(u & 0xffff0000u); }
__device__ __forceinline__ ushort f2bf(float x){ __hip_bfloat16 h = __float2bfloat16(x); return *(ushort*)&h; }
__device__ __forceinline__ uint pk2(float a, float b){ return (uint)f2bf(a) | ((uint)f2bf(b) << 16); }

// ---------------- MFMA GEMM (unchanged from round 3) ----------------
template<bool ABF16, bool PROJ>
__global__ __launch_bounds__(512) void gemm_mfma(const void* __restrict__ Av,
    const float* __restrict__ W, const float* __restrict__ bias,
    void* __restrict__ Dv, float* __restrict__ rnorm) {
  __shared__ __align__(16) char AlB[128*64*2];
  __shared__ __align__(16) char WlB[256*64*2];
  __shared__ float rnp[128][4];
  const int t  = threadIdx.x;
  const int p0 = blockIdx.x * 128;
  const int lane = t & 63;
  const int w  = t >> 6;
  const int wr = w >> 2, wc = w & 3;

  int aoff[2]; size_t agb[2];
  #pragma unroll
  for (int i = 0; i < 2; ++i) {
    int c = t + i*512, row = c >> 3, cc = c & 7;
    aoff[i] = row*128 + ((cc*16) ^ ((row & 7) << 4));
    agb[i]  = (size_t)(p0 + row)*CC + cc*8;
  }
  int woff[4]; size_t wgb[4];
  #pragma unroll
  for (int i = 0; i < 4; ++i) {
    int c = t + i*512, row = c >> 3, cc = c & 7;
    woff[i] = row*128 + ((cc*16) ^ ((row & 7) << 4));
    wgb[i]  = (size_t)row*CC + cc*8;
  }
  const int arow = (wr << 6) + (lane & 31);
  const int brow = (wc << 6) + (lane & 31);
  const int kb0  = (lane >> 5) << 4;

  uint4 ra[2], rw[4];
  auto LOADA = [&](int ks) {
    #pragma unroll
    for (int i = 0; i < 2; ++i) {
      if constexpr (ABF16) {
        ra[i] = *(const uint4*)((const ushort*)Av + agb[i] + ks*64);
      } else {
        const float* A = (const float*)Av;
        float4 v0 = *(const float4*)(A + agb[i] + ks*64);
        float4 v1 = *(const float4*)(A + agb[i] + ks*64 + 4);
        ra[i] = make_uint4(pk2(v0.x,v0.y), pk2(v0.z,v0.w), pk2(v1.x,v1.y), pk2(v1.z,v1.w));
      }
    }
  };
  auto LOADW = [&](int ks) {
    #pragma unroll
    for (int i = 0; i < 4; ++i) {
      float4 v0 = *(const float4*)(W + wgb[i] + ks*64);
      float4 v1 = *(const float4*)(W + wgb[i] + ks*64 + 4);
      rw[i] = make_uint4(pk2(v0.x,v0.y), pk2(v0.z,v0.w), pk2(v1.x,v1.y), pk2(v1.z,v1.w));
    }
  };
  auto WRITE = [&]() {
    #pragma unroll
    for (int i = 0; i < 2; ++i) *(uint4*)(AlB + aoff[i]) = ra[i];
    #pragma unroll
    for (int i = 0; i < 4; ++i) *(uint4*)(WlB + woff[i]) = rw[i];
  };

  f32x16 acc[2][2];
  #pragma unroll
  for (int fm = 0; fm < 2; ++fm)
    #pragma unroll
    for (int fn = 0; fn < 2; ++fn)
      #pragma unroll
      for (int r = 0; r < 16; ++r) acc[fm][fn][r] = 0.0f;

  LOADA(0); LOADW(0);
  WRITE();
  __syncthreads();

  #pragma unroll
  for (int ks = 0; ks < 4; ++ks) {
    if (ks < 3) { LOADA(ks+1); LOADW(ks+1); }
    bf16x8 af[2][4], bg[2][4];
    #pragma unroll
    for (int fm = 0; fm < 2; ++fm)
      #pragma unroll
      for (int kq = 0; kq < 4; ++kq) {
        int row = arow + (fm << 5);
        int off = row*128 + (((kq << 5) + kb0) ^ ((row & 7) << 4));
        af[fm][kq] = *(const bf16x8*)(AlB + off);
      }
    #pragma unroll
    for (int fn = 0; fn < 2; ++fn)
      #pragma unroll
      for (int kq = 0; kq < 4; ++kq) {
        int row = brow + (fn << 5);
        int off = row*128 + (((kq << 5) + kb0) ^ ((row & 7) << 4));
        bg[fn][kq] = *(const bf16x8*)(WlB + off);
      }
    #pragma unroll
    for (int kq = 0; kq < 4; ++kq)
      #pragma unroll
      for (int fm = 0; fm < 2; ++fm)
        #pragma unroll
        for (int fn = 0; fn < 2; ++fn)
          acc[fm][fn] = __builtin_amdgcn_mfma_f32_32x32x16_bf16(
              af[fm][kq], bg[fn][kq], acc[fm][fn], 0, 0, 0);
    __syncthreads();
    if (ks < 3) { WRITE(); __syncthreads(); }
  }

  const int colb = (wc << 6) + (lane & 31);
  const float b0 = bias[colb], b1 = bias[colb + 32];
  #pragma unroll
  for (int fm = 0; fm < 2; ++fm) {
    float rs[16];
    #pragma unroll
    for (int r = 0; r < 16; ++r) {
      int rowin = (r & 3) + ((r >> 2) << 3) + ((lane >> 5) << 2);
      size_t grow = (size_t)(p0 + (wr << 6) + (fm << 5) + rowin);
      float v0 = acc[fm][0][r] + b0;
      float v1 = acc[fm][1][r] + b1;
      if constexpr (PROJ) {
        ushort* D = (ushort*)Dv;
        D[grow*CC + colb]      = f2bf(v0);
        D[grow*CC + colb + 32] = f2bf(v1);
        rs[r] = v0*v0 + v1*v1;
      } else {
        float* D = (float*)Dv;
        D[grow*CC + colb]      = v0;
        D[grow*CC + colb + 32] = v1;
      }
    }
    if constexpr (PROJ) {
      #pragma unroll
      for (int m = 1; m < 32; m <<= 1)
        #pragma unroll
        for (int r = 0; r < 16; ++r) rs[r] += __shfl_xor(rs[r], m);
      if ((lane & 31) == 0) {
        #pragma unroll
        for (int r = 0; r < 16; ++r) {
          int rowin = (r & 3) + ((r >> 2) << 3) + ((lane >> 5) << 2);
          rnp[(wr << 6) + (fm << 5) + rowin][wc] = rs[r];
        }
      }
    }
  }
  if constexpr (PROJ) {
    __syncthreads();
    if (t < 128) {
      float s = rnp[t][0] + rnp[t][1] + rnp[t][2] + rnp[t][3];
      rnorm[p0 + t] = 1.0f / fmaxf(sqrtf(s), 1e-12f);
    }
  }
}

// ---------------- tiny kernels ----------------
__global__ void init_centers(const ushort* __restrict__ nbf, float* __restrict__ centers) {
  const int idx[8] = {0, 2340, 4680, 7021, 9361, 11702, 14042, 16383};
  int b = blockIdx.x >> 3, k = blockIdx.x & 7;
  int c = threadIdx.x;
  centers[(size_t)(b*NCLUS + k)*CC + c] =
      __uint_as_float(((uint)nbf[((size_t)b*PP + idx[k])*CC + c]) << 16);
}

// centers(f32) -> cnormbf(bf16); zero acc slots + counts
__global__ __launch_bounds__(256) void center_norm_init(const float* __restrict__ centers,
    ushort* __restrict__ cnormbf, float* __restrict__ accs, float* __restrict__ counts) {
  const int row = blockIdx.x;
  const int t = threadIdx.x;
  float c = centers[(size_t)row*CC + t];
  float s2 = c*c;
  #pragma unroll
  for (int o = 32; o; o >>= 1) s2 += __shfl_xor(s2, o);
  __shared__ float ps[4];
  if ((t & 63) == 0) ps[t >> 6] = s2;
  __syncthreads();
  float tot = ps[0] + ps[1] + ps[2] + ps[3];
  cnormbf[(size_t)row*CC + t] = f2bf(c * (1.0f / fmaxf(sqrtf(tot), 1e-12f)));
  #pragma unroll
  for (int s = 0; s < 8; ++s) accs[((size_t)s*64 + row)*CC + t] = 0.0f;
  if (t == 0) counts[row] = 0.0f;
}

// accs -> new centers; emit cnormbf (bf16) + transposed ctbf[col][k] (bf16); re-zero
__global__ __launch_bounds__(256) void centers_finalize(float* __restrict__ accs,
    float* __restrict__ counts, ushort* __restrict__ cnormbf, ushort* __restrict__ ctbf) {
  const int row = blockIdx.x;            // b*8 + k
  const int b = row >> 3, k = row & 7;
  const int t = threadIdx.x;
  float v = 0.0f;
  #pragma unroll
  for (int s = 0; s < 8; ++s) {
    v += accs[((size_t)s*64 + row)*CC + t];
    accs[((size_t)s*64 + row)*CC + t] = 0.0f;
  }
  float cnt = fmaxf(counts[row], 1.0f);
  float c = v / cnt;
  ctbf[(size_t)b*CC*NCLUS + t*NCLUS + k] = f2bf(c);
  float s2 = c*c;
  #pragma unroll
  for (int o = 32; o; o >>= 1) s2 += __shfl_xor(s2, o);
  __shared__ float ps[4];
  if ((t & 63) == 0) ps[t >> 6] = s2;
  __syncthreads();
  float tot = ps[0] + ps[1] + ps[2] + ps[3];
  cnormbf[(size_t)row*CC + t] = f2bf(c * (1.0f / fmaxf(sqrtf(tot), 1e-12f)));
  if (t == 0) counts[row] = 0.0f;
}

// ---------------- MFMA sims: one wave computes 8 sims for 32 points ----------------
// A = cnormbf rows (clusters, rows>=8 zeroed), B = nbf rows (points).
// After shfl_xor(32): every lane holds all 8 sims of point (lane&31).
__device__ __forceinline__ void sims_mfma(const ushort* __restrict__ nb_base,
    const ushort* __restrict__ cnb, int lane, float* s) {
  const int pcol = lane & 31;
  const int kb   = (lane >> 5) << 3;          // k-slice base (elems)
  const ushort* arow = cnb + (size_t)(pcol & 7)*CC + kb;
  const ushort* brow = nb_base + (size_t)pcol*CC + kb;
  const bool azero = pcol >= 8;
  bf16x8 z;
  #pragma unroll
  for (int j = 0; j < 8; ++j) z[j] = (__bf16)0.0f;
  f32x16 acc;
  #pragma unroll
  for (int r = 0; r < 16; ++r) acc[r] = 0.0f;
  #pragma unroll
  for (int st = 0; st < 16; ++st) {
    bf16x8 af = *(const bf16x8*)(arow + st*16);
    if (azero) af = z;
    bf16x8 bg = *(const bf16x8*)(brow + st*16);
    acc = __builtin_amdgcn_mfma_f32_32x32x16_bf16(af, bg, acc, 0, 0, 0);
  }
  // regs 0..3: lane<32 -> clusters 0..3 of point pcol; lane>=32 -> clusters 4..7
  float sh[4];
  #pragma unroll
  for (int r = 0; r < 4; ++r) sh[r] = __shfl_xor(acc[r], 32);
  const bool hi = lane >= 32;
  #pragma unroll
  for (int r = 0; r < 4; ++r) {
    s[r]     = hi ? sh[r]  : acc[r];
    s[r + 4] = hi ? acc[r] : sh[r];
  }
}

// ---------------- assign: MFMA sims + argmax, column-parallel accumulate ----------------
__global__ __launch_bounds__(256) void assign_mfma(const ushort* __restrict__ nbf,
    const ushort* __restrict__ cnormbf, float* __restrict__ accs, float* __restrict__ counts) {
  __shared__ int assignL[128];
  __shared__ int cntL[NCLUS];
  const int t = threadIdx.x;
  const int wave = t >> 6, lane = t & 63;
  const int b = blockIdx.x >> 7;                 // 128 blocks per batch
  if (t < NCLUS) cntL[t] = 0;
  __syncthreads();
  const size_t p0w = (size_t)blockIdx.x*128 + wave*32;
  float s[8];
  sims_mfma(nbf + p0w*CC, cnormbf + (size_t)b*NCLUS*CC, lane, s);
  if (lane < 32) {
    int best = 0; float bs = s[0];
    #pragma unroll
    for (int k = 1; k < 8; ++k) if (s[k] > bs) { bs = s[k]; best = k; }
    assignL[wave*32 + lane] = best;
    atomicAdd(&cntL[best], 1);
  }
  __syncthreads();
  // phase 2: column t over 128 points (L1/L2-hot re-read)
  float a[8] = {0,0,0,0,0,0,0,0};
  const ushort* base = nbf + (size_t)blockIdx.x*128*CC;
  #pragma unroll 4
  for (int i = 0; i < 128; ++i) {
    int asg = __builtin_amdgcn_readfirstlane(assignL[i]);
    float v = __uint_as_float(((uint)base[(size_t)i*CC + t]) << 16);
    if      (asg == 0) a[0] += v;
    else if (asg == 1) a[1] += v;
    else if (asg == 2) a[2] += v;
    else if (asg == 3) a[3] += v;
    else if (asg == 4) a[4] += v;
    else if (asg == 5) a[5] += v;
    else if (asg == 6) a[6] += v;
    else               a[7] += v;
  }
  const int slot = blockIdx.x & 7;
  float* dst = accs + ((size_t)slot*BB + b)*NCLUS*CC;
  #pragma unroll
  for (int k = 0; k < 8; ++k) atomicAdd(&dst[k*CC + t], a[k]);
  if (t < NCLUS) atomicAdd(&counts[b*NCLUS + t], (float)cntL[t]);
}

// ---------------- fuse: MFMA sims -> softmax -> MFMA blend + residual ----------------
__global__ __launch_bounds__(256) void fuse_mfma(const ushort* __restrict__ nbf,
    const float* __restrict__ F_p, const ushort* __restrict__ cnormbf,
    const ushort* __restrict__ ctbf, const float* __restrict__ rnorm,
    ushort* __restrict__ tbf) {
  const int t = threadIdx.x;
  const int wave = t >> 6, lane = t & 63;
  const int b = blockIdx.x >> 7;
  const size_t p0w = (size_t)blockIdx.x*128 + wave*32;
  float s[8];
  sims_mfma(nbf + p0w*CC, cnormbf + (size_t)b*NCLUS*CC, lane, s);
  const int pcol = lane & 31;
  const float rn10 = rnorm[p0w + pcol] * 10.0f;
  float m = -1e30f;
  #pragma unroll
  for (int k = 0; k < 8; ++k) { s[k] *= rn10; m = fmaxf(m, s[k]); }
  float wgt[8], sw = 0.0f;
  #pragma unroll
  for (int k = 0; k < 8; ++k) { wgt[k] = __expf(s[k] - m); sw += wgt[k]; }
  const float inv = 1.0f / sw;
  // A-operand for blend: lane<32 holds the 8 weights of its point (k=0..7); lanes>=32 are K-pad -> 0
  bf16x8 aw;
  #pragma unroll
  for (int k = 0; k < 8; ++k) aw[k] = (__bf16)0.0f;
  if (lane < 32) {
    #pragma unroll
    for (int k = 0; k < 8; ++k) aw[k] = (__bf16)(wgt[k] * inv);
  }
  const ushort* ct = ctbf + (size_t)b*CC*NCLUS;
  const int kb = (lane >> 5) << 3;
  #pragma unroll
  for (int cb = 0; cb < 8; ++cb) {
    // B-operand: lane holds col (cb*32 + pcol), k-slice kb..kb+7 (garbage for kb=8, killed by aw=0)
    bf16x8 bg = *(const bf16x8*)(ct + (size_t)(cb*32 + pcol)*NCLUS + kb);
    f32x16 d;
    #pragma unroll
    for (int r = 0; r < 16; ++r) d[r] = 0.0f;
    d = __builtin_amdgcn_mfma_f32_32x32x16_bf16(aw, bg, d, 0, 0, 0);
    const int col = cb*32 + pcol;
    #pragma unroll
    for (int r = 0; r < 16; ++r) {
      int row = (r & 3) + ((r >> 2) << 3) + ((lane >> 5) << 2);
      size_t off = (p0w + row)*CC + col;
      tbf[off] = f2bf(d[r] + F_p[off]);
    }
  }
}

extern "C" void kernel_launch(void* const* d_in, const int* in_sizes, int n_in,
                              void* d_out, int out_size, void* d_ws, size_t ws_size,
                              hipStream_t stream) {
  const float* F_p      = (const float*)d_in[0];
  const float* proj_w   = (const float*)d_in[1];
  const float* proj_b   = (const float*)d_in[2];
  const float* refine_w = (const float*)d_in[3];
  const float* refine_b = (const float*)d_in[4];
  float* out = (float*)d_out;

  char* ws = (char*)d_ws;
  ushort* nbf    = (ushort*)ws;                                    // 64 MiB
  ushort* tbf    = (ushort*)(ws + (size_t)BPROWS*CC*2);            // 64 MiB
  float*  rnorm  = (float*)(ws + (size_t)BPROWS*CC*4);             // 512 KiB
  float*  centers= rnorm + BPROWS;                                 // 64 KiB
  float*  accs   = centers + BB*NCLUS*CC;                          // 512 KiB (8 slots)
  float*  counts = accs + 8*BB*NCLUS*CC;                           // 256 B
  ushort* cnormbf= (ushort*)(counts + 64);                         // 32 KiB
  ushort* ctbf   = cnormbf + BB*NCLUS*CC;                          // 32 KiB (+tail pad below)

  gemm_mfma<false, true><<<1024, 512, 0, stream>>>(F_p, proj_w, proj_b, nbf, rnorm);
  init_centers<<<64, 256, 0, stream>>>(nbf, centers);
  center_norm_init<<<64, 256, 0, stream>>>(centers, cnormbf, accs, counts);
  for (int it = 0; it < 3; ++it) {
    assign_mfma<<<1024, 256, 0, stream>>>(nbf, cnormbf, accs, counts);
    centers_finalize<<<64, 256, 0, stream>>>(accs, counts, cnormbf, ctbf);
  }
  fuse_mfma<<<1024, 256, 0, stream>>>(nbf, F_p, cnormbf, ctbf, rnorm, tbf);
  gemm_mfma<true, false><<<1024, 512, 0, stream>>>(tbf, refine_w, refine_b, out, nullptr);
}

// Round 6
// 361.075 us; speedup vs baseline: 1.3609x; 1.0215x over previous
//
#include <hip/hip_runtime.h>
#include <hip/hip_bf16.h>
#include <cmath>

#define BB 8
#define PP 16384
#define CC 256
#define NCLUS 8
#define BPROWS (BB*PP)

typedef unsigned int uint;
typedef unsigned short ushort;
typedef __bf16 bf16x8 __attribute__((ext_vector_type(8)));
typedef float f32x16 __attribute__((ext_vector_type(16)));

__device__ __forceinline__ float bflo(uint u){ return __uint_as_float(u << 16); }
__device__ __forceinline__ float bfhi(uint u){ return __uint_as_float(u & 0xffff0000u); }
__device__ __forceinline__ ushort f2bf(float x){ __hip_bfloat16 h = __float2bfloat16(x); return *(ushort*)&h; }
__device__ __forceinline__ uint pk2(float a, float b){ return (uint)f2bf(a) | ((uint)f2bf(b) << 16); }

// ---------------- one-shot bf16 conversion of both weight matrices ----------------
__global__ __launch_bounds__(256) void wcvt(const float* __restrict__ Wp,
    const float* __restrict__ Wr, ushort* __restrict__ Wpb, ushort* __restrict__ Wrb) {
  int i = blockIdx.x*256 + threadIdx.x;          // 16384 threads x 4 elems
  float4 a = *(const float4*)(Wp + (size_t)i*4);
  float4 b = *(const float4*)(Wr + (size_t)i*4);
  *(uint2*)(Wpb + (size_t)i*4) = make_uint2(pk2(a.x,a.y), pk2(a.z,a.w));
  *(uint2*)(Wrb + (size_t)i*4) = make_uint2(pk2(b.x,b.y), pk2(b.z,b.w));
}

// ---------------- MFMA GEMM ----------------
// D = A @ Wb^T + bias.  A: 131072x256 fp32 (cast to bf16 in staging), Wb: 256x256 bf16.
// PROJ: D bf16 + per-row rnorm.  !PROJ: D fp32 + rank-8 correction W8@CR.
template<bool PROJ>
__global__ __launch_bounds__(512) void gemm_mfma(const float* __restrict__ A,
    const ushort* __restrict__ Wb, const float* __restrict__ bias,
    void* __restrict__ Dv, float* __restrict__ rnorm,
    const float* __restrict__ W8, const float* __restrict__ CR) {
  __shared__ __align__(16) char AlB[128*64*2];   // 16 KB, swizzled bf16 A tile
  __shared__ __align__(16) char WlB[256*64*2];   // 32 KB, swizzled bf16 W tile
  __shared__ float rnp[128][4];
  const int t  = threadIdx.x;
  const int p0 = blockIdx.x * 128;
  const int lane = t & 63;
  const int w  = t >> 6;
  const int wr = w >> 2, wc = w & 3;

  int aoff[2]; size_t agb[2];
  #pragma unroll
  for (int i = 0; i < 2; ++i) {
    int c = t + i*512, row = c >> 3, cc = c & 7;
    aoff[i] = row*128 + ((cc*16) ^ ((row & 7) << 4));
    agb[i]  = (size_t)(p0 + row)*CC + cc*8;
  }
  int woff[4]; size_t wgb[4];
  #pragma unroll
  for (int i = 0; i < 4; ++i) {
    int c = t + i*512, row = c >> 3, cc = c & 7;
    woff[i] = row*128 + ((cc*16) ^ ((row & 7) << 4));
    wgb[i]  = (size_t)row*CC + cc*8;
  }
  const int arow = (wr << 6) + (lane & 31);
  const int brow = (wc << 6) + (lane & 31);
  const int kb0  = (lane >> 5) << 4;

  uint4 ra[2], rw[4];
  auto LOADA = [&](int ks) {
    #pragma unroll
    for (int i = 0; i < 2; ++i) {
      float4 v0 = *(const float4*)(A + agb[i] + ks*64);
      float4 v1 = *(const float4*)(A + agb[i] + ks*64 + 4);
      ra[i] = make_uint4(pk2(v0.x,v0.y), pk2(v0.z,v0.w), pk2(v1.x,v1.y), pk2(v1.z,v1.w));
    }
  };
  auto LOADW = [&](int ks) {
    #pragma unroll
    for (int i = 0; i < 4; ++i)
      rw[i] = *(const uint4*)(Wb + wgb[i] + ks*64);
  };
  auto WRITE = [&]() {
    #pragma unroll
    for (int i = 0; i < 2; ++i) *(uint4*)(AlB + aoff[i]) = ra[i];
    #pragma unroll
    for (int i = 0; i < 4; ++i) *(uint4*)(WlB + woff[i]) = rw[i];
  };

  f32x16 acc[2][2];
  #pragma unroll
  for (int fm = 0; fm < 2; ++fm)
    #pragma unroll
    for (int fn = 0; fn < 2; ++fn)
      #pragma unroll
      for (int r = 0; r < 16; ++r) acc[fm][fn][r] = 0.0f;

  LOADA(0); LOADW(0);
  WRITE();
  __syncthreads();

  #pragma unroll
  for (int ks = 0; ks < 4; ++ks) {
    if (ks < 3) { LOADA(ks+1); LOADW(ks+1); }   // in flight under ds_read+MFMA
    bf16x8 af[2][4], bg[2][4];
    #pragma unroll
    for (int fm = 0; fm < 2; ++fm)
      #pragma unroll
      for (int kq = 0; kq < 4; ++kq) {
        int row = arow + (fm << 5);
        int off = row*128 + (((kq << 5) + kb0) ^ ((row & 7) << 4));
        af[fm][kq] = *(const bf16x8*)(AlB + off);
      }
    #pragma unroll
    for (int fn = 0; fn < 2; ++fn)
      #pragma unroll
      for (int kq = 0; kq < 4; ++kq) {
        int row = brow + (fn << 5);
        int off = row*128 + (((kq << 5) + kb0) ^ ((row & 7) << 4));
        bg[fn][kq] = *(const bf16x8*)(WlB + off);
      }
    #pragma unroll
    for (int kq = 0; kq < 4; ++kq)
      #pragma unroll
      for (int fm = 0; fm < 2; ++fm)
        #pragma unroll
        for (int fn = 0; fn < 2; ++fn)
          acc[fm][fn] = __builtin_amdgcn_mfma_f32_32x32x16_bf16(
              af[fm][kq], bg[fn][kq], acc[fm][fn], 0, 0, 0);
    __syncthreads();
    if (ks < 3) { WRITE(); __syncthreads(); }
  }

  // --- epilogue ---
  const int colb = (wc << 6) + (lane & 31);
  const float b0 = bias[colb], b1 = bias[colb + 32];
  float cr0[8], cr1[8];
  if constexpr (!PROJ) {
    const float* crb = CR + (size_t)(blockIdx.x >> 7)*NCLUS*CC;
    #pragma unroll
    for (int k = 0; k < 8; ++k) { cr0[k] = crb[k*CC + colb]; cr1[k] = crb[k*CC + colb + 32]; }
  }
  #pragma unroll
  for (int fm = 0; fm < 2; ++fm) {
    float rs[16];
    #pragma unroll
    for (int r = 0; r < 16; ++r) {
      int rowin = (r & 3) + ((r >> 2) << 3) + ((lane >> 5) << 2);
      size_t grow = (size_t)(p0 + (wr << 6) + (fm << 5) + rowin);
      float v0 = acc[fm][0][r] + b0;
      float v1 = acc[fm][1][r] + b1;
      if constexpr (PROJ) {
        ushort* D = (ushort*)Dv;
        D[grow*CC + colb]      = f2bf(v0);
        D[grow*CC + colb + 32] = f2bf(v1);
        rs[r] = v0*v0 + v1*v1;
      } else {
        float4 ua = *(const float4*)(W8 + grow*8);      // half-wave-broadcast rows
        float4 ub = *(const float4*)(W8 + grow*8 + 4);
        v0 += ua.x*cr0[0] + ua.y*cr0[1] + ua.z*cr0[2] + ua.w*cr0[3]
            + ub.x*cr0[4] + ub.y*cr0[5] + ub.z*cr0[6] + ub.w*cr0[7];
        v1 += ua.x*cr1[0] + ua.y*cr1[1] + ua.z*cr1[2] + ua.w*cr1[3]
            + ub.x*cr1[4] + ub.y*cr1[5] + ub.z*cr1[6] + ub.w*cr1[7];
        float* D = (float*)Dv;
        D[grow*CC + colb]      = v0;
        D[grow*CC + colb + 32] = v1;
      }
    }
    if constexpr (PROJ) {
      #pragma unroll
      for (int m = 1; m < 32; m <<= 1)
        #pragma unroll
        for (int r = 0; r < 16; ++r) rs[r] += __shfl_xor(rs[r], m);
      if ((lane & 31) == 0) {
        #pragma unroll
        for (int r = 0; r < 16; ++r) {
          int rowin = (r & 3) + ((r >> 2) << 3) + ((lane >> 5) << 2);
          rnp[(wr << 6) + (fm << 5) + rowin][wc] = rs[r];
        }
      }
    }
  }
  if constexpr (PROJ) {
    __syncthreads();
    if (t < 128) {
      float s = rnp[t][0] + rnp[t][1] + rnp[t][2] + rnp[t][3];
      rnorm[p0 + t] = 1.0f / fmaxf(sqrtf(s), 1e-12f);
    }
  }
}

// ---------------- tiny kernels ----------------
__global__ void init_centers(const ushort* __restrict__ nbf, float* __restrict__ centers) {
  const int idx[8] = {0, 2340, 4680, 7021, 9361, 11702, 14042, 16383};
  int b = blockIdx.x >> 3, k = blockIdx.x & 7;
  int c = threadIdx.x;
  centers[(size_t)(b*NCLUS + k)*CC + c] =
      __uint_as_float(((uint)nbf[((size_t)b*PP + idx[k])*CC + c]) << 16);
}

__global__ __launch_bounds__(256) void center_norm_init(const float* __restrict__ centers,
    ushort* __restrict__ cnormbf, float* __restrict__ accs, float* __restrict__ counts) {
  const int row = blockIdx.x;
  const int t = threadIdx.x;
  float c = centers[(size_t)row*CC + t];
  float s2 = c*c;
  #pragma unroll
  for (int o = 32; o; o >>= 1) s2 += __shfl_xor(s2, o);
  __shared__ float ps[4];
  if ((t & 63) == 0) ps[t >> 6] = s2;
  __syncthreads();
  float tot = ps[0] + ps[1] + ps[2] + ps[3];
  cnormbf[(size_t)row*CC + t] = f2bf(c * (1.0f / fmaxf(sqrtf(tot), 1e-12f)));
  #pragma unroll
  for (int s = 0; s < 8; ++s) accs[((size_t)s*64 + row)*CC + t] = 0.0f;
  if (t == 0) counts[row] = 0.0f;
}

// accs -> new centers (f32) + cnormbf (bf16); re-zero accs/counts
__global__ __launch_bounds__(256) void centers_finalize(float* __restrict__ accs,
    float* __restrict__ counts, ushort* __restrict__ cnormbf, float* __restrict__ centers) {
  const int row = blockIdx.x;
  const int t = threadIdx.x;
  float v = 0.0f;
  #pragma unroll
  for (int s = 0; s < 8; ++s) {
    v += accs[((size_t)s*64 + row)*CC + t];
    accs[((size_t)s*64 + row)*CC + t] = 0.0f;
  }
  float cnt = fmaxf(counts[row], 1.0f);
  float c = v / cnt;
  centers[(size_t)row*CC + t] = c;
  float s2 = c*c;
  #pragma unroll
  for (int o = 32; o; o >>= 1) s2 += __shfl_xor(s2, o);
  __shared__ float ps[4];
  if ((t & 63) == 0) ps[t >> 6] = s2;
  __syncthreads();
  float tot = ps[0] + ps[1] + ps[2] + ps[3];
  cnormbf[(size_t)row*CC + t] = f2bf(c * (1.0f / fmaxf(sqrtf(tot), 1e-12f)));
  if (t == 0) counts[row] = 0.0f;
}

// CR[b][k][c] = dot(centers[b][k][:], Wr[c][:])   (8 blocks, thread = col)
__global__ __launch_bounds__(256) void cr8_compute(const float* __restrict__ centers,
    const float* __restrict__ Wr, float* __restrict__ CR) {
  __shared__ float cenL[NCLUS][CC];
  const int b = blockIdx.x;
  const int t = threadIdx.x;
  for (int i = t; i < NCLUS*CC; i += 256)
    ((float*)cenL)[i] = centers[(size_t)b*NCLUS*CC + i];
  __syncthreads();
  float a8[8] = {0,0,0,0,0,0,0,0};
  const float* wrow = Wr + (size_t)t*CC;
  for (int j = 0; j < CC; j += 4) {
    float4 wv = *(const float4*)(wrow + j);
    #pragma unroll
    for (int k = 0; k < 8; ++k) {
      float4 cv = *(const float4*)&cenL[k][j];
      a8[k] += cv.x*wv.x + cv.y*wv.y + cv.z*wv.z + cv.w*wv.w;
    }
  }
  #pragma unroll
  for (int k = 0; k < 8; ++k) CR[((size_t)b*NCLUS + k)*CC + t] = a8[k];
}

// ---------------- MFMA sims: one wave computes 8 sims for 32 points ----------------
__device__ __forceinline__ void sims_mfma(const ushort* __restrict__ nb_base,
    const ushort* __restrict__ cnb, int lane, float* s) {
  const int pcol = lane & 31;
  const int kb   = (lane >> 5) << 3;
  const ushort* arow = cnb + (size_t)(pcol & 7)*CC + kb;
  const ushort* brow = nb_base + (size_t)pcol*CC + kb;
  const bool azero = pcol >= 8;
  bf16x8 z;
  #pragma unroll
  for (int j = 0; j < 8; ++j) z[j] = (__bf16)0.0f;
  f32x16 acc;
  #pragma unroll
  for (int r = 0; r < 16; ++r) acc[r] = 0.0f;
  #pragma unroll
  for (int st = 0; st < 16; ++st) {
    bf16x8 af = *(const bf16x8*)(arow + st*16);
    if (azero) af = z;
    bf16x8 bg = *(const bf16x8*)(brow + st*16);
    acc = __builtin_amdgcn_mfma_f32_32x32x16_bf16(af, bg, acc, 0, 0, 0);
  }
  float sh[4];
  #pragma unroll
  for (int r = 0; r < 4; ++r) sh[r] = __shfl_xor(acc[r], 32);
  const bool hi = lane >= 32;
  #pragma unroll
  for (int r = 0; r < 4; ++r) {
    s[r]     = hi ? sh[r]  : acc[r];
    s[r + 4] = hi ? acc[r] : sh[r];
  }
}

// ---------------- assign: MFMA sims + argmax, column-parallel accumulate ----------------
__global__ __launch_bounds__(256) void assign_mfma(const ushort* __restrict__ nbf,
    const ushort* __restrict__ cnormbf, float* __restrict__ accs, float* __restrict__ counts) {
  __shared__ int assignL[128];
  __shared__ int cntL[NCLUS];
  const int t = threadIdx.x;
  const int wave = t >> 6, lane = t & 63;
  const int b = blockIdx.x >> 7;
  if (t < NCLUS) cntL[t] = 0;
  __syncthreads();
  const size_t p0w = (size_t)blockIdx.x*128 + wave*32;
  float s[8];
  sims_mfma(nbf + p0w*CC, cnormbf + (size_t)b*NCLUS*CC, lane, s);
  if (lane < 32) {
    int best = 0; float bs = s[0];
    #pragma unroll
    for (int k = 1; k < 8; ++k) if (s[k] > bs) { bs = s[k]; best = k; }
    assignL[wave*32 + lane] = best;
    atomicAdd(&cntL[best], 1);
  }
  __syncthreads();
  float a[8] = {0,0,0,0,0,0,0,0};
  const ushort* base = nbf + (size_t)blockIdx.x*128*CC;
  #pragma unroll 4
  for (int i = 0; i < 128; ++i) {
    int asg = __builtin_amdgcn_readfirstlane(assignL[i]);
    float v = __uint_as_float(((uint)base[(size_t)i*CC + t]) << 16);
    if      (asg == 0) a[0] += v;
    else if (asg == 1) a[1] += v;
    else if (asg == 2) a[2] += v;
    else if (asg == 3) a[3] += v;
    else if (asg == 4) a[4] += v;
    else if (asg == 5) a[5] += v;
    else if (asg == 6) a[6] += v;
    else               a[7] += v;
  }
  const int slot = blockIdx.x & 7;
  float* dst = accs + ((size_t)slot*BB + b)*NCLUS*CC;
  #pragma unroll
  for (int k = 0; k < 8; ++k) atomicAdd(&dst[k*CC + t], a[k]);
  if (t < NCLUS) atomicAdd(&counts[b*NCLUS + t], (float)cntL[t]);
}

// ---------------- fuse: MFMA sims -> softmax -> W8 (fp32 weights, 4 MB) ----------------
__global__ __launch_bounds__(256) void fuse_w8(const ushort* __restrict__ nbf,
    const ushort* __restrict__ cnormbf, const float* __restrict__ rnorm,
    float* __restrict__ W8) {
  const int t = threadIdx.x;
  const int wave = t >> 6, lane = t & 63;
  const int b = blockIdx.x >> 7;
  const size_t p0w = (size_t)blockIdx.x*128 + wave*32;
  float s[8];
  sims_mfma(nbf + p0w*CC, cnormbf + (size_t)b*NCLUS*CC, lane, s);
  const int pcol = lane & 31;
  const float rn10 = rnorm[p0w + pcol] * 10.0f;
  float m = -1e30f;
  #pragma unroll
  for (int k = 0; k < 8; ++k) { s[k] *= rn10; m = fmaxf(m, s[k]); }
  float wgt[8], sw = 0.0f;
  #pragma unroll
  for (int k = 0; k < 8; ++k) { wgt[k] = __expf(s[k] - m); sw += wgt[k]; }
  const float inv = 1.0f / sw;
  if (lane < 32) {
    float* wp = W8 + (p0w + pcol)*8;
    *(float4*)(wp)     = make_float4(wgt[0]*inv, wgt[1]*inv, wgt[2]*inv, wgt[3]*inv);
    *(float4*)(wp + 4) = make_float4(wgt[4]*inv, wgt[5]*inv, wgt[6]*inv, wgt[7]*inv);
  }
}

extern "C" void kernel_launch(void* const* d_in, const int* in_sizes, int n_in,
                              void* d_out, int out_size, void* d_ws, size_t ws_size,
                              hipStream_t stream) {
  const float* F_p      = (const float*)d_in[0];
  const float* proj_w   = (const float*)d_in[1];
  const float* proj_b   = (const float*)d_in[2];
  const float* refine_w = (const float*)d_in[3];
  const float* refine_b = (const float*)d_in[4];
  float* out = (float*)d_out;

  char* ws = (char*)d_ws;
  ushort* nbf    = (ushort*)ws;                                  // 64 MiB
  float*  rnorm  = (float*)(ws + (size_t)BPROWS*CC*2);           // 512 KiB
  float*  centers= rnorm + BPROWS;                               // 64 KiB
  float*  accs   = centers + BB*NCLUS*CC;                        // 512 KiB
  float*  counts = accs + 8*BB*NCLUS*CC;                         // 256 B
  float*  CR     = counts + 64;                                  // 64 KiB
  ushort* cnormbf= (ushort*)(CR + BB*NCLUS*CC);                  // 32 KiB
  ushort* Wpb    = cnormbf + BB*NCLUS*CC;                        // 128 KiB
  ushort* Wrb    = Wpb + CC*CC;                                  // 128 KiB
  float*  W8     = (float*)(Wrb + CC*CC);                        // 4 MiB

  wcvt<<<64, 256, 0, stream>>>(proj_w, refine_w, Wpb, Wrb);
  gemm_mfma<true><<<1024, 512, 0, stream>>>(F_p, Wpb, proj_b, nbf, rnorm, nullptr, nullptr);
  init_centers<<<64, 256, 0, stream>>>(nbf, centers);
  center_norm_init<<<64, 256, 0, stream>>>(centers, cnormbf, accs, counts);
  for (int it = 0; it < 3; ++it) {
    assign_mfma<<<1024, 256, 0, stream>>>(nbf, cnormbf, accs, counts);
    centers_finalize<<<64, 256, 0, stream>>>(accs, counts, cnormbf, centers);
  }
  fuse_w8<<<1024, 256, 0, stream>>>(nbf, cnormbf, rnorm, W8);
  cr8_compute<<<8, 256, 0, stream>>>(centers, refine_w, CR);
  gemm_mfma<false><<<1024, 512, 0, stream>>>(F_p, Wrb, refine_b, out, nullptr, W8, CR);
}

// Round 7
// 303.131 us; speedup vs baseline: 1.6211x; 1.1912x over previous
//
#include <hip/hip_runtime.h>
#include <hip/hip_bf16.h>
#include <cmath>

#define BB 8
#define PP 16384
#define CC 256
#define NCLUS 8
#define BPROWS (BB*PP)

typedef unsigned int uint;
typedef unsigned short ushort;
typedef __bf16 bf16x8 __attribute__((ext_vector_type(8)));
typedef float f32x16 __attribute__((ext_vector_type(16)));

__device__ __forceinline__ float bflo(uint u){ return __uint_as_float(u << 16); }
__device__ __forceinline__ float bfhi(uint u){ return __uint_as_float(u & 0xffff0000u); }
__device__ __forceinline__ ushort f2bf(float x){ __hip_bfloat16 h = __float2bfloat16(x); return *(ushort*)&h; }
__device__ __forceinline__ uint pk2(float a, float b){ return (uint)f2bf(a) | ((uint)f2bf(b) << 16); }

// ---------------- one-shot bf16 conversion of both weight matrices ----------------
__global__ __launch_bounds__(256) void wcvt(const float* __restrict__ Wp,
    const float* __restrict__ Wr, ushort* __restrict__ Wpb, ushort* __restrict__ Wrb) {
  int i = blockIdx.x*256 + threadIdx.x;          // 16384 threads x 4 elems
  float4 a = *(const float4*)(Wp + (size_t)i*4);
  float4 b = *(const float4*)(Wr + (size_t)i*4);
  *(uint2*)(Wpb + (size_t)i*4) = make_uint2(pk2(a.x,a.y), pk2(a.z,a.w));
  *(uint2*)(Wrb + (size_t)i*4) = make_uint2(pk2(b.x,b.y), pk2(b.z,b.w));
}

// ---------------- F_p -> bf16 (16 elems/thread, 8192 blocks) ----------------
__global__ __launch_bounds__(256) void fcvt(const float* __restrict__ F, ushort* __restrict__ fb) {
  size_t i = ((size_t)blockIdx.x*256 + threadIdx.x) * 16;
  float4 a = *(const float4*)(F + i);
  float4 b = *(const float4*)(F + i + 4);
  float4 c = *(const float4*)(F + i + 8);
  float4 d = *(const float4*)(F + i + 12);
  *(uint4*)(fb + i)     = make_uint4(pk2(a.x,a.y), pk2(a.z,a.w), pk2(b.x,b.y), pk2(b.z,b.w));
  *(uint4*)(fb + i + 8) = make_uint4(pk2(c.x,c.y), pk2(c.z,c.w), pk2(d.x,d.y), pk2(d.z,d.w));
}

// ---------------- MFMA GEMM, global_load_lds staging ----------------
// D = A @ Wb^T + bias.  A (bf16 131072x256), Wb (bf16 256x256, row-major).
// PROJ: D bf16 + per-row rnorm.  !PROJ: D fp32 + rank-8 correction W8@CR.
// LDS layout: linear slots S=(row, sc) of 16B; slot holds global chunk (sc ^ (row&7))
// (inverse-swizzled SOURCE, linear DEST, swizzled READ — m173 pattern).
template<bool PROJ>
__global__ __launch_bounds__(512) void gemm_bf16(const ushort* __restrict__ Ab,
    const ushort* __restrict__ Wb, const float* __restrict__ bias,
    void* __restrict__ Dv, float* __restrict__ rnorm,
    const float* __restrict__ W8, const float* __restrict__ CR) {
  __shared__ __align__(16) char AlB[128*64*2];   // 16 KB
  __shared__ __align__(16) char WlB[256*64*2];   // 32 KB
  __shared__ float rnp[128][4];
  const int t  = threadIdx.x;
  const int p0 = blockIdx.x * 128;
  const int lane = t & 63;
  const int w  = t >> 6;
  const int wr = w >> 2, wc = w & 3;

  // staging address maps (per-thread global source, linear LDS dest)
  const ushort* asrc[2]; char* adst[2];
  #pragma unroll
  for (int i = 0; i < 2; ++i) {
    int S = i*512 + t, row = S >> 3, sc = S & 7;
    asrc[i] = Ab + (size_t)(p0 + row)*CC + ((sc ^ (row & 7)) << 3);
    adst[i] = AlB + (size_t)S*16;
  }
  const ushort* wsrc[4]; char* wdst[4];
  #pragma unroll
  for (int i = 0; i < 4; ++i) {
    int S = i*512 + t, row = S >> 3, sc = S & 7;
    wsrc[i] = Wb + (size_t)row*CC + ((sc ^ (row & 7)) << 3);
    wdst[i] = WlB + (size_t)S*16;
  }
  const int arow = (wr << 6) + (lane & 31);
  const int brow = (wc << 6) + (lane & 31);
  const int kb0  = (lane >> 5) << 4;

  f32x16 acc[2][2];
  #pragma unroll
  for (int fm = 0; fm < 2; ++fm)
    #pragma unroll
    for (int fn = 0; fn < 2; ++fn)
      #pragma unroll
      for (int r = 0; r < 16; ++r) acc[fm][fn][r] = 0.0f;

  #pragma unroll
  for (int ks = 0; ks < 4; ++ks) {
    // ---- stage tile ks: 6 x global_load_lds_dwordx4, no VGPR round-trip
    #pragma unroll
    for (int i = 0; i < 2; ++i)
      __builtin_amdgcn_global_load_lds(
          (const __attribute__((address_space(1))) uint*)(asrc[i] + ks*64),
          (__attribute__((address_space(3))) uint*)adst[i], 16, 0, 0);
    #pragma unroll
    for (int i = 0; i < 4; ++i)
      __builtin_amdgcn_global_load_lds(
          (const __attribute__((address_space(1))) uint*)(wsrc[i] + ks*64),
          (__attribute__((address_space(3))) uint*)wdst[i], 16, 0, 0);
    __syncthreads();            // vmcnt drain: LDS tile ready
    // ---- consume
    bf16x8 af[2][4], bg[2][4];
    #pragma unroll
    for (int fm = 0; fm < 2; ++fm)
      #pragma unroll
      for (int kq = 0; kq < 4; ++kq) {
        int row = arow + (fm << 5);
        int off = row*128 + (((kq << 5) + kb0) ^ ((row & 7) << 4));
        af[fm][kq] = *(const bf16x8*)(AlB + off);
      }
    #pragma unroll
    for (int fn = 0; fn < 2; ++fn)
      #pragma unroll
      for (int kq = 0; kq < 4; ++kq) {
        int row = brow + (fn << 5);
        int off = row*128 + (((kq << 5) + kb0) ^ ((row & 7) << 4));
        bg[fn][kq] = *(const bf16x8*)(WlB + off);
      }
    #pragma unroll
    for (int kq = 0; kq < 4; ++kq)
      #pragma unroll
      for (int fm = 0; fm < 2; ++fm)
        #pragma unroll
        for (int fn = 0; fn < 2; ++fn)
          acc[fm][fn] = __builtin_amdgcn_mfma_f32_32x32x16_bf16(
              af[fm][kq], bg[fn][kq], acc[fm][fn], 0, 0, 0);
    if (ks < 3) __syncthreads();   // reads done before next stage overwrites
  }

  // --- epilogue ---
  const int colb = (wc << 6) + (lane & 31);
  const float b0 = bias[colb], b1 = bias[colb + 32];
  float cr0[8], cr1[8];
  if constexpr (!PROJ) {
    const float* crb = CR + (size_t)(blockIdx.x >> 7)*NCLUS*CC;
    #pragma unroll
    for (int k = 0; k < 8; ++k) { cr0[k] = crb[k*CC + colb]; cr1[k] = crb[k*CC + colb + 32]; }
  }
  #pragma unroll
  for (int fm = 0; fm < 2; ++fm) {
    float rs[16];
    #pragma unroll
    for (int r = 0; r < 16; ++r) {
      int rowin = (r & 3) + ((r >> 2) << 3) + ((lane >> 5) << 2);
      size_t grow = (size_t)(p0 + (wr << 6) + (fm << 5) + rowin);
      float v0 = acc[fm][0][r] + b0;
      float v1 = acc[fm][1][r] + b1;
      if constexpr (PROJ) {
        ushort* D = (ushort*)Dv;
        D[grow*CC + colb]      = f2bf(v0);
        D[grow*CC + colb + 32] = f2bf(v1);
        rs[r] = v0*v0 + v1*v1;
      } else {
        float4 ua = *(const float4*)(W8 + grow*8);
        float4 ub = *(const float4*)(W8 + grow*8 + 4);
        v0 += ua.x*cr0[0] + ua.y*cr0[1] + ua.z*cr0[2] + ua.w*cr0[3]
            + ub.x*cr0[4] + ub.y*cr0[5] + ub.z*cr0[6] + ub.w*cr0[7];
        v1 += ua.x*cr1[0] + ua.y*cr1[1] + ua.z*cr1[2] + ua.w*cr1[3]
            + ub.x*cr1[4] + ub.y*cr1[5] + ub.z*cr1[6] + ub.w*cr1[7];
        float* D = (float*)Dv;
        D[grow*CC + colb]      = v0;
        D[grow*CC + colb + 32] = v1;
      }
    }
    if constexpr (PROJ) {
      #pragma unroll
      for (int m = 1; m < 32; m <<= 1)
        #pragma unroll
        for (int r = 0; r < 16; ++r) rs[r] += __shfl_xor(rs[r], m);
      if ((lane & 31) == 0) {
        #pragma unroll
        for (int r = 0; r < 16; ++r) {
          int rowin = (r & 3) + ((r >> 2) << 3) + ((lane >> 5) << 2);
          rnp[(wr << 6) + (fm << 5) + rowin][wc] = rs[r];
        }
      }
    }
  }
  if constexpr (PROJ) {
    __syncthreads();
    if (t < 128) {
      float s = rnp[t][0] + rnp[t][1] + rnp[t][2] + rnp[t][3];
      rnorm[p0 + t] = 1.0f / fmaxf(sqrtf(s), 1e-12f);
    }
  }
}

// ---------------- tiny kernels ----------------
__global__ void init_centers(const ushort* __restrict__ nbf, float* __restrict__ centers) {
  const int idx[8] = {0, 2340, 4680, 7021, 9361, 11702, 14042, 16383};
  int b = blockIdx.x >> 3, k = blockIdx.x & 7;
  int c = threadIdx.x;
  centers[(size_t)(b*NCLUS + k)*CC + c] =
      __uint_as_float(((uint)nbf[((size_t)b*PP + idx[k])*CC + c]) << 16);
}

__global__ __launch_bounds__(256) void center_norm_init(const float* __restrict__ centers,
    ushort* __restrict__ cnormbf, float* __restrict__ accs, float* __restrict__ counts) {
  const int row = blockIdx.x;
  const int t = threadIdx.x;
  float c = centers[(size_t)row*CC + t];
  float s2 = c*c;
  #pragma unroll
  for (int o = 32; o; o >>= 1) s2 += __shfl_xor(s2, o);
  __shared__ float ps[4];
  if ((t & 63) == 0) ps[t >> 6] = s2;
  __syncthreads();
  float tot = ps[0] + ps[1] + ps[2] + ps[3];
  cnormbf[(size_t)row*CC + t] = f2bf(c * (1.0f / fmaxf(sqrtf(tot), 1e-12f)));
  #pragma unroll
  for (int s = 0; s < 8; ++s) accs[((size_t)s*64 + row)*CC + t] = 0.0f;
  if (t == 0) counts[row] = 0.0f;
}

__global__ __launch_bounds__(256) void centers_finalize(float* __restrict__ accs,
    float* __restrict__ counts, ushort* __restrict__ cnormbf, float* __restrict__ centers) {
  const int row = blockIdx.x;
  const int t = threadIdx.x;
  float v = 0.0f;
  #pragma unroll
  for (int s = 0; s < 8; ++s) {
    v += accs[((size_t)s*64 + row)*CC + t];
    accs[((size_t)s*64 + row)*CC + t] = 0.0f;
  }
  float cnt = fmaxf(counts[row], 1.0f);
  float c = v / cnt;
  centers[(size_t)row*CC + t] = c;
  float s2 = c*c;
  #pragma unroll
  for (int o = 32; o; o >>= 1) s2 += __shfl_xor(s2, o);
  __shared__ float ps[4];
  if ((t & 63) == 0) ps[t >> 6] = s2;
  __syncthreads();
  float tot = ps[0] + ps[1] + ps[2] + ps[3];
  cnormbf[(size_t)row*CC + t] = f2bf(c * (1.0f / fmaxf(sqrtf(tot), 1e-12f)));
  if (t == 0) counts[row] = 0.0f;
}

// CR[b][k][c] = dot(centers[b][k][:], Wr[c][:])
__global__ __launch_bounds__(256) void cr8_compute(const float* __restrict__ centers,
    const float* __restrict__ Wr, float* __restrict__ CR) {
  __shared__ float cenL[NCLUS][CC];
  const int b = blockIdx.x;
  const int t = threadIdx.x;
  for (int i = t; i < NCLUS*CC; i += 256)
    ((float*)cenL)[i] = centers[(size_t)b*NCLUS*CC + i];
  __syncthreads();
  float a8[8] = {0,0,0,0,0,0,0,0};
  const float* wrow = Wr + (size_t)t*CC;
  for (int j = 0; j < CC; j += 4) {
    float4 wv = *(const float4*)(wrow + j);
    #pragma unroll
    for (int k = 0; k < 8; ++k) {
      float4 cv = *(const float4*)&cenL[k][j];
      a8[k] += cv.x*wv.x + cv.y*wv.y + cv.z*wv.z + cv.w*wv.w;
    }
  }
  #pragma unroll
  for (int k = 0; k < 8; ++k) CR[((size_t)b*NCLUS + k)*CC + t] = a8[k];
}

// ---------------- MFMA sims: one wave computes 8 sims for 32 points ----------------
__device__ __forceinline__ void sims_mfma(const ushort* __restrict__ nb_base,
    const ushort* __restrict__ cnb, int lane, float* s) {
  const int pcol = lane & 31;
  const int kb   = (lane >> 5) << 3;
  const ushort* arow = cnb + (size_t)(pcol & 7)*CC + kb;
  const ushort* brow = nb_base + (size_t)pcol*CC + kb;
  const bool azero = pcol >= 8;
  bf16x8 z;
  #pragma unroll
  for (int j = 0; j < 8; ++j) z[j] = (__bf16)0.0f;
  f32x16 acc;
  #pragma unroll
  for (int r = 0; r < 16; ++r) acc[r] = 0.0f;
  #pragma unroll
  for (int st = 0; st < 16; ++st) {
    bf16x8 af = *(const bf16x8*)(arow + st*16);
    if (azero) af = z;
    bf16x8 bg = *(const bf16x8*)(brow + st*16);
    acc = __builtin_amdgcn_mfma_f32_32x32x16_bf16(af, bg, acc, 0, 0, 0);
  }
  float sh[4];
  #pragma unroll
  for (int r = 0; r < 4; ++r) sh[r] = __shfl_xor(acc[r], 32);
  const bool hi = lane >= 32;
  #pragma unroll
  for (int r = 0; r < 4; ++r) {
    s[r]     = hi ? sh[r]  : acc[r];
    s[r + 4] = hi ? acc[r] : sh[r];
  }
}

// ---------------- assign: MFMA sims + argmax, column-parallel accumulate ----------------
__global__ __launch_bounds__(256) void assign_mfma(const ushort* __restrict__ nbf,
    const ushort* __restrict__ cnormbf, float* __restrict__ accs, float* __restrict__ counts) {
  __shared__ int assignL[128];
  __shared__ int cntL[NCLUS];
  const int t = threadIdx.x;
  const int wave = t >> 6, lane = t & 63;
  const int b = blockIdx.x >> 7;
  if (t < NCLUS) cntL[t] = 0;
  __syncthreads();
  const size_t p0w = (size_t)blockIdx.x*128 + wave*32;
  float s[8];
  sims_mfma(nbf + p0w*CC, cnormbf + (size_t)b*NCLUS*CC, lane, s);
  if (lane < 32) {
    int best = 0; float bs = s[0];
    #pragma unroll
    for (int k = 1; k < 8; ++k) if (s[k] > bs) { bs = s[k]; best = k; }
    assignL[wave*32 + lane] = best;
    atomicAdd(&cntL[best], 1);
  }
  __syncthreads();
  float a[8] = {0,0,0,0,0,0,0,0};
  const ushort* base = nbf + (size_t)blockIdx.x*128*CC;
  #pragma unroll 4
  for (int i = 0; i < 128; ++i) {
    int asg = __builtin_amdgcn_readfirstlane(assignL[i]);
    float v = __uint_as_float(((uint)base[(size_t)i*CC + t]) << 16);
    if      (asg == 0) a[0] += v;
    else if (asg == 1) a[1] += v;
    else if (asg == 2) a[2] += v;
    else if (asg == 3) a[3] += v;
    else if (asg == 4) a[4] += v;
    else if (asg == 5) a[5] += v;
    else if (asg == 6) a[6] += v;
    else               a[7] += v;
  }
  const int slot = blockIdx.x & 7;
  float* dst = accs + ((size_t)slot*BB + b)*NCLUS*CC;
  #pragma unroll
  for (int k = 0; k < 8; ++k) atomicAdd(&dst[k*CC + t], a[k]);
  if (t < NCLUS) atomicAdd(&counts[b*NCLUS + t], (float)cntL[t]);
}

// ---------------- fuse: MFMA sims -> softmax -> W8 (fp32, 4 MB) ----------------
__global__ __launch_bounds__(256) void fuse_w8(const ushort* __restrict__ nbf,
    const ushort* __restrict__ cnormbf, const float* __restrict__ rnorm,
    float* __restrict__ W8) {
  const int t = threadIdx.x;
  const int wave = t >> 6, lane = t & 63;
  const int b = blockIdx.x >> 7;
  const size_t p0w = (size_t)blockIdx.x*128 + wave*32;
  float s[8];
  sims_mfma(nbf + p0w*CC, cnormbf + (size_t)b*NCLUS*CC, lane, s);
  const int pcol = lane & 31;
  const float rn10 = rnorm[p0w + pcol] * 10.0f;
  float m = -1e30f;
  #pragma unroll
  for (int k = 0; k < 8; ++k) { s[k] *= rn10; m = fmaxf(m, s[k]); }
  float wgt[8], sw = 0.0f;
  #pragma unroll
  for (int k = 0; k < 8; ++k) { wgt[k] = __expf(s[k] - m); sw += wgt[k]; }
  const float inv = 1.0f / sw;
  if (lane < 32) {
    float* wp = W8 + (p0w + pcol)*8;
    *(float4*)(wp)     = make_float4(wgt[0]*inv, wgt[1]*inv, wgt[2]*inv, wgt[3]*inv);
    *(float4*)(wp + 4) = make_float4(wgt[4]*inv, wgt[5]*inv, wgt[6]*inv, wgt[7]*inv);
  }
}

extern "C" void kernel_launch(void* const* d_in, const int* in_sizes, int n_in,
                              void* d_out, int out_size, void* d_ws, size_t ws_size,
                              hipStream_t stream) {
  const float* F_p      = (const float*)d_in[0];
  const float* proj_w   = (const float*)d_in[1];
  const float* proj_b   = (const float*)d_in[2];
  const float* refine_w = (const float*)d_in[3];
  const float* refine_b = (const float*)d_in[4];
  float* out = (float*)d_out;

  char* ws = (char*)d_ws;
  ushort* nbf    = (ushort*)ws;                                  // 64 MiB
  ushort* fbf    = (ushort*)(ws + (size_t)BPROWS*CC*2);          // 64 MiB
  float*  rnorm  = (float*)(ws + (size_t)BPROWS*CC*4);           // 512 KiB
  float*  centers= rnorm + BPROWS;                               // 64 KiB
  float*  accs   = centers + BB*NCLUS*CC;                        // 512 KiB
  float*  counts = accs + 8*BB*NCLUS*CC;                         // 256 B
  float*  CR     = counts + 64;                                  // 64 KiB
  ushort* cnormbf= (ushort*)(CR + BB*NCLUS*CC);                  // 32 KiB
  ushort* Wpb    = cnormbf + BB*NCLUS*CC;                        // 128 KiB
  ushort* Wrb    = Wpb + CC*CC;                                  // 128 KiB
  float*  W8     = (float*)(Wrb + CC*CC);                        // 4 MiB

  wcvt<<<64, 256, 0, stream>>>(proj_w, refine_w, Wpb, Wrb);
  fcvt<<<8192, 256, 0, stream>>>(F_p, fbf);
  gemm_bf16<true><<<1024, 512, 0, stream>>>(fbf, Wpb, proj_b, nbf, rnorm, nullptr, nullptr);
  init_centers<<<64, 256, 0, stream>>>(nbf, centers);
  center_norm_init<<<64, 256, 0, stream>>>(centers, cnormbf, accs, counts);
  for (int it = 0; it < 3; ++it) {
    assign_mfma<<<1024, 256, 0, stream>>>(nbf, cnormbf, accs, counts);
    centers_finalize<<<64, 256, 0, stream>>>(accs, counts, cnormbf, centers);
  }
  fuse_w8<<<1024, 256, 0, stream>>>(nbf, cnormbf, rnorm, W8);
  cr8_compute<<<8, 256, 0, stream>>>(centers, refine_w, CR);
  gemm_bf16<false><<<1024, 512, 0, stream>>>(fbf, Wrb, refine_b, out, nullptr, W8, CR);
}

// Round 8
// 285.023 us; speedup vs baseline: 1.7240x; 1.0635x over previous
//
#include <hip/hip_runtime.h>
#include <hip/hip_bf16.h>
#include <cmath>

#define BB 8
#define PP 16384
#define CC 256
#define NCLUS 8
#define BPROWS (BB*PP)

typedef unsigned int uint;
typedef unsigned short ushort;
typedef __bf16 bf16x8 __attribute__((ext_vector_type(8)));
typedef float f32x16 __attribute__((ext_vector_type(16)));

__device__ __forceinline__ float bflo(uint u){ return __uint_as_float(u << 16); }
__device__ __forceinline__ float bfhi(uint u){ return __uint_as_float(u & 0xffff0000u); }
__device__ __forceinline__ ushort f2bf(float x){ __hip_bfloat16 h = __float2bfloat16(x); return *(ushort*)&h; }
__device__ __forceinline__ uint pk2(float a, float b){ return (uint)f2bf(a) | ((uint)f2bf(b) << 16); }

// ---------------- one-shot bf16 conversion of both weight matrices ----------------
__global__ __launch_bounds__(256) void wcvt(const float* __restrict__ Wp,
    const float* __restrict__ Wr, ushort* __restrict__ Wpb, ushort* __restrict__ Wrb) {
  int i = blockIdx.x*256 + threadIdx.x;
  float4 a = *(const float4*)(Wp + (size_t)i*4);
  float4 b = *(const float4*)(Wr + (size_t)i*4);
  *(uint2*)(Wpb + (size_t)i*4) = make_uint2(pk2(a.x,a.y), pk2(a.z,a.w));
  *(uint2*)(Wrb + (size_t)i*4) = make_uint2(pk2(b.x,b.y), pk2(b.z,b.w));
}

// ---------------- MFMA GEMM ----------------
// PROJ: A = F_p f32, reg-staged (cvt in staging), writes fbf bf16 + D bf16 + rnorm.
// !PROJ: A = fbf bf16 via global_load_lds (inverse-swizzled source), D fp32 + W8@CR.
// W: always bf16 via global_load_lds (inverse-swizzled source, linear dest, swizzled read).
template<bool PROJ>
__global__ __launch_bounds__(512) void gemm_bf16(const void* __restrict__ Av,
    const ushort* __restrict__ Wb, const float* __restrict__ bias,
    void* __restrict__ Dv, float* __restrict__ rnorm,
    const float* __restrict__ W8, const float* __restrict__ CR,
    ushort* __restrict__ fbf) {
  __shared__ __align__(16) char AlB[128*64*2];   // 16 KB
  __shared__ __align__(16) char WlB[256*64*2];   // 32 KB
  __shared__ float rnp[128][4];
  const int t  = threadIdx.x;
  const int p0 = blockIdx.x * 128;
  const int lane = t & 63;
  const int w  = t >> 6;
  const int wr = w >> 2, wc = w & 3;

  // ---- A staging maps
  // PROJ (reg-staged): linear global source chunk cc, swizzled LDS dest.
  // !PROJ (gload_lds): inverse-swizzled global source, linear LDS dest.
  int aoff[2]; size_t agb[2];
  const ushort* asrc[2]; char* adst[2];
  #pragma unroll
  for (int i = 0; i < 2; ++i) {
    int S = i*512 + t, row = S >> 3, sc = S & 7;
    if constexpr (PROJ) {
      aoff[i] = row*128 + ((sc*16) ^ ((row & 7) << 4));   // swizzled LDS byte
      agb[i]  = (size_t)(p0 + row)*CC + sc*8;             // linear global elem
    } else {
      asrc[i] = (const ushort*)Av + (size_t)(p0 + row)*CC + ((sc ^ (row & 7)) << 3);
      adst[i] = AlB + (size_t)S*16;
    }
  }
  const ushort* wsrc[4]; char* wdst[4];
  #pragma unroll
  for (int i = 0; i < 4; ++i) {
    int S = i*512 + t, row = S >> 3, sc = S & 7;
    wsrc[i] = Wb + (size_t)row*CC + ((sc ^ (row & 7)) << 3);
    wdst[i] = WlB + (size_t)S*16;
  }
  const int arow = (wr << 6) + (lane & 31);
  const int brow = (wc << 6) + (lane & 31);
  const int kb0  = (lane >> 5) << 4;

  uint4 ra[2];
  auto LOADA = [&](int ks) {         // PROJ only: f32 -> packed bf16 regs
    const float* A = (const float*)Av;
    #pragma unroll
    for (int i = 0; i < 2; ++i) {
      float4 v0 = *(const float4*)(A + agb[i] + ks*64);
      float4 v1 = *(const float4*)(A + agb[i] + ks*64 + 4);
      ra[i] = make_uint4(pk2(v0.x,v0.y), pk2(v0.z,v0.w), pk2(v1.x,v1.y), pk2(v1.z,v1.w));
    }
  };
  auto WRITEA = [&](int ks) {        // PROJ only: LDS (swizzled) + fbf (linear)
    #pragma unroll
    for (int i = 0; i < 2; ++i) {
      *(uint4*)(AlB + aoff[i]) = ra[i];
      *(uint4*)(fbf + agb[i] + ks*64) = ra[i];
    }
  };
  auto STAGEA_LDS = [&](int ks) {    // !PROJ only
    #pragma unroll
    for (int i = 0; i < 2; ++i)
      __builtin_amdgcn_global_load_lds(
          (const __attribute__((address_space(1))) uint*)(asrc[i] + ks*64),
          (__attribute__((address_space(3))) uint*)adst[i], 16, 0, 0);
  };
  auto STAGEW = [&](int ks) {
    #pragma unroll
    for (int i = 0; i < 4; ++i)
      __builtin_amdgcn_global_load_lds(
          (const __attribute__((address_space(1))) uint*)(wsrc[i] + ks*64),
          (__attribute__((address_space(3))) uint*)wdst[i], 16, 0, 0);
  };

  f32x16 acc[2][2];
  #pragma unroll
  for (int fm = 0; fm < 2; ++fm)
    #pragma unroll
    for (int fn = 0; fn < 2; ++fn)
      #pragma unroll
      for (int r = 0; r < 16; ++r) acc[fm][fn][r] = 0.0f;

  // ---- prologue: stage tile 0
  if constexpr (PROJ) {
    LOADA(0); STAGEW(0); WRITEA(0);
  } else {
    STAGEA_LDS(0); STAGEW(0);
  }
  __syncthreads();                    // vmcnt/ds drain: tile 0 ready

  #pragma unroll
  for (int ks = 0; ks < 4; ++ks) {
    if constexpr (PROJ) { if (ks < 3) LOADA(ks+1); }  // next A in flight under MFMA
    bf16x8 af[2][4], bg[2][4];
    #pragma unroll
    for (int fm = 0; fm < 2; ++fm)
      #pragma unroll
      for (int kq = 0; kq < 4; ++kq) {
        int row = arow + (fm << 5);
        int off = row*128 + (((kq << 5) + kb0) ^ ((row & 7) << 4));
        af[fm][kq] = *(const bf16x8*)(AlB + off);
      }
    #pragma unroll
    for (int fn = 0; fn < 2; ++fn)
      #pragma unroll
      for (int kq = 0; kq < 4; ++kq) {
        int row = brow + (fn << 5);
        int off = row*128 + (((kq << 5) + kb0) ^ ((row & 7) << 4));
        bg[fn][kq] = *(const bf16x8*)(WlB + off);
      }
    #pragma unroll
    for (int kq = 0; kq < 4; ++kq)
      #pragma unroll
      for (int fm = 0; fm < 2; ++fm)
        #pragma unroll
        for (int fn = 0; fn < 2; ++fn)
          acc[fm][fn] = __builtin_amdgcn_mfma_f32_32x32x16_bf16(
              af[fm][kq], bg[fn][kq], acc[fm][fn], 0, 0, 0);
    if (ks < 3) {
      __syncthreads();                // tile ks reads complete
      if constexpr (PROJ) { STAGEW(ks+1); WRITEA(ks+1); }
      else               { STAGEA_LDS(ks+1); STAGEW(ks+1); }
      __syncthreads();                // tile ks+1 ready
    }
  }

  // --- epilogue ---
  const int colb = (wc << 6) + (lane & 31);
  const float b0 = bias[colb], b1 = bias[colb + 32];
  float cr0[8], cr1[8];
  if constexpr (!PROJ) {
    const float* crb = CR + (size_t)(blockIdx.x >> 7)*NCLUS*CC;
    #pragma unroll
    for (int k = 0; k < 8; ++k) { cr0[k] = crb[k*CC + colb]; cr1[k] = crb[k*CC + colb + 32]; }
  }
  #pragma unroll
  for (int fm = 0; fm < 2; ++fm) {
    float rs[16];
    #pragma unroll
    for (int r = 0; r < 16; ++r) {
      int rowin = (r & 3) + ((r >> 2) << 3) + ((lane >> 5) << 2);
      size_t grow = (size_t)(p0 + (wr << 6) + (fm << 5) + rowin);
      float v0 = acc[fm][0][r] + b0;
      float v1 = acc[fm][1][r] + b1;
      if constexpr (PROJ) {
        ushort* D = (ushort*)Dv;
        D[grow*CC + colb]      = f2bf(v0);
        D[grow*CC + colb + 32] = f2bf(v1);
        rs[r] = v0*v0 + v1*v1;
      } else {
        float4 ua = *(const float4*)(W8 + grow*8);
        float4 ub = *(const float4*)(W8 + grow*8 + 4);
        v0 += ua.x*cr0[0] + ua.y*cr0[1] + ua.z*cr0[2] + ua.w*cr0[3]
            + ub.x*cr0[4] + ub.y*cr0[5] + ub.z*cr0[6] + ub.w*cr0[7];
        v1 += ua.x*cr1[0] + ua.y*cr1[1] + ua.z*cr1[2] + ua.w*cr1[3]
            + ub.x*cr1[4] + ub.y*cr1[5] + ub.z*cr1[6] + ub.w*cr1[7];
        float* D = (float*)Dv;
        D[grow*CC + colb]      = v0;
        D[grow*CC + colb + 32] = v1;
      }
    }
    if constexpr (PROJ) {
      #pragma unroll
      for (int m = 1; m < 32; m <<= 1)
        #pragma unroll
        for (int r = 0; r < 16; ++r) rs[r] += __shfl_xor(rs[r], m);
      if ((lane & 31) == 0) {
        #pragma unroll
        for (int r = 0; r < 16; ++r) {
          int rowin = (r & 3) + ((r >> 2) << 3) + ((lane >> 5) << 2);
          rnp[(wr << 6) + (fm << 5) + rowin][wc] = rs[r];
        }
      }
    }
  }
  if constexpr (PROJ) {
    __syncthreads();
    if (t < 128) {
      float s = rnp[t][0] + rnp[t][1] + rnp[t][2] + rnp[t][3];
      rnorm[p0 + t] = 1.0f / fmaxf(sqrtf(s), 1e-12f);
    }
  }
}

// ---------------- merged: init centers from nodes + norm + zero accs ----------------
__global__ __launch_bounds__(256) void centers_init(const ushort* __restrict__ nbf,
    float* __restrict__ centers, ushort* __restrict__ cnormbf,
    float* __restrict__ accs, float* __restrict__ counts) {
  const int idxs[8] = {0, 2340, 4680, 7021, 9361, 11702, 14042, 16383};
  const int row = blockIdx.x;            // b*8 + k
  const int b = row >> 3, k = row & 7;
  const int t = threadIdx.x;
  float c = __uint_as_float(((uint)nbf[((size_t)b*PP + idxs[k])*CC + t]) << 16);
  centers[(size_t)row*CC + t] = c;
  float s2 = c*c;
  #pragma unroll
  for (int o = 32; o; o >>= 1) s2 += __shfl_xor(s2, o);
  __shared__ float ps[4];
  if ((t & 63) == 0) ps[t >> 6] = s2;
  __syncthreads();
  float tot = ps[0] + ps[1] + ps[2] + ps[3];
  cnormbf[(size_t)row*CC + t] = f2bf(c * (1.0f / fmaxf(sqrtf(tot), 1e-12f)));
  #pragma unroll
  for (int s = 0; s < 8; ++s) accs[((size_t)s*64 + row)*CC + t] = 0.0f;
  if (t == 0) counts[row] = 0.0f;
}

__global__ __launch_bounds__(256) void centers_finalize(float* __restrict__ accs,
    float* __restrict__ counts, ushort* __restrict__ cnormbf, float* __restrict__ centers) {
  const int row = blockIdx.x;
  const int t = threadIdx.x;
  float v = 0.0f;
  #pragma unroll
  for (int s = 0; s < 8; ++s) {
    v += accs[((size_t)s*64 + row)*CC + t];
    accs[((size_t)s*64 + row)*CC + t] = 0.0f;
  }
  float cnt = fmaxf(counts[row], 1.0f);
  float c = v / cnt;
  centers[(size_t)row*CC + t] = c;
  float s2 = c*c;
  #pragma unroll
  for (int o = 32; o; o >>= 1) s2 += __shfl_xor(s2, o);
  __shared__ float ps[4];
  if ((t & 63) == 0) ps[t >> 6] = s2;
  __syncthreads();
  float tot = ps[0] + ps[1] + ps[2] + ps[3];
  cnormbf[(size_t)row*CC + t] = f2bf(c * (1.0f / fmaxf(sqrtf(tot), 1e-12f)));
  if (t == 0) counts[row] = 0.0f;
}

// CR[b][k][c] = dot(centers[b][k][:], Wr[c][:])  — 64 blocks, one dot per thread
__global__ __launch_bounds__(256) void cr8_compute(const float* __restrict__ centers,
    const float* __restrict__ Wr, float* __restrict__ CR) {
  __shared__ float cenL[CC];
  const int row = blockIdx.x;            // b*8 + k
  const int t = threadIdx.x;
  cenL[t] = centers[(size_t)row*CC + t];
  __syncthreads();
  float a = 0.0f;
  const float* wrow = Wr + (size_t)t*CC;
  #pragma unroll 4
  for (int j = 0; j < CC; j += 4) {
    float4 wv = *(const float4*)(wrow + j);
    float4 cv = *(const float4*)&cenL[j];
    a += cv.x*wv.x + cv.y*wv.y + cv.z*wv.z + cv.w*wv.w;
  }
  CR[(size_t)row*CC + t] = a;
}

// ---------------- MFMA sims: one wave computes 8 sims for 32 points ----------------
__device__ __forceinline__ void sims_mfma(const ushort* __restrict__ nb_base,
    const ushort* __restrict__ cnb, int lane, float* s) {
  const int pcol = lane & 31;
  const int kb   = (lane >> 5) << 3;
  const ushort* arow = cnb + (size_t)(pcol & 7)*CC + kb;
  const ushort* brow = nb_base + (size_t)pcol*CC + kb;
  const bool azero = pcol >= 8;
  bf16x8 z;
  #pragma unroll
  for (int j = 0; j < 8; ++j) z[j] = (__bf16)0.0f;
  f32x16 acc;
  #pragma unroll
  for (int r = 0; r < 16; ++r) acc[r] = 0.0f;
  #pragma unroll
  for (int st = 0; st < 16; ++st) {
    bf16x8 af = *(const bf16x8*)(arow + st*16);
    if (azero) af = z;
    bf16x8 bg = *(const bf16x8*)(brow + st*16);
    acc = __builtin_amdgcn_mfma_f32_32x32x16_bf16(af, bg, acc, 0, 0, 0);
  }
  float sh[4];
  #pragma unroll
  for (int r = 0; r < 4; ++r) sh[r] = __shfl_xor(acc[r], 32);
  const bool hi = lane >= 32;
  #pragma unroll
  for (int r = 0; r < 4; ++r) {
    s[r]     = hi ? sh[r]  : acc[r];
    s[r + 4] = hi ? acc[r] : sh[r];
  }
}

// ---------------- assign: MFMA sims + argmax, column-parallel accumulate ----------------
__global__ __launch_bounds__(256) void assign_mfma(const ushort* __restrict__ nbf,
    const ushort* __restrict__ cnormbf, float* __restrict__ accs, float* __restrict__ counts) {
  __shared__ int assignL[128];
  __shared__ int cntL[NCLUS];
  const int t = threadIdx.x;
  const int wave = t >> 6, lane = t & 63;
  const int b = blockIdx.x >> 7;
  if (t < NCLUS) cntL[t] = 0;
  __syncthreads();
  const size_t p0w = (size_t)blockIdx.x*128 + wave*32;
  float s[8];
  sims_mfma(nbf + p0w*CC, cnormbf + (size_t)b*NCLUS*CC, lane, s);
  if (lane < 32) {
    int best = 0; float bs = s[0];
    #pragma unroll
    for (int k = 1; k < 8; ++k) if (s[k] > bs) { bs = s[k]; best = k; }
    assignL[wave*32 + lane] = best;
    atomicAdd(&cntL[best], 1);
  }
  __syncthreads();
  float a[8] = {0,0,0,0,0,0,0,0};
  const ushort* base = nbf + (size_t)blockIdx.x*128*CC;
  #pragma unroll 4
  for (int i = 0; i < 128; ++i) {
    int asg = __builtin_amdgcn_readfirstlane(assignL[i]);
    float v = __uint_as_float(((uint)base[(size_t)i*CC + t]) << 16);
    if      (asg == 0) a[0] += v;
    else if (asg == 1) a[1] += v;
    else if (asg == 2) a[2] += v;
    else if (asg == 3) a[3] += v;
    else if (asg == 4) a[4] += v;
    else if (asg == 5) a[5] += v;
    else if (asg == 6) a[6] += v;
    else               a[7] += v;
  }
  const int slot = blockIdx.x & 7;
  float* dst = accs + ((size_t)slot*BB + b)*NCLUS*CC;
  #pragma unroll
  for (int k = 0; k < 8; ++k) atomicAdd(&dst[k*CC + t], a[k]);
  if (t < NCLUS) atomicAdd(&counts[b*NCLUS + t], (float)cntL[t]);
}

// ---------------- fuse: MFMA sims -> softmax -> W8 (fp32, 4 MB) ----------------
__global__ __launch_bounds__(256) void fuse_w8(const ushort* __restrict__ nbf,
    const ushort* __restrict__ cnormbf, const float* __restrict__ rnorm,
    float* __restrict__ W8) {
  const int t = threadIdx.x;
  const int wave = t >> 6, lane = t & 63;
  const int b = blockIdx.x >> 7;
  const size_t p0w = (size_t)blockIdx.x*128 + wave*32;
  float s[8];
  sims_mfma(nbf + p0w*CC, cnormbf + (size_t)b*NCLUS*CC, lane, s);
  const int pcol = lane & 31;
  const float rn10 = rnorm[p0w + pcol] * 10.0f;
  float m = -1e30f;
  #pragma unroll
  for (int k = 0; k < 8; ++k) { s[k] *= rn10; m = fmaxf(m, s[k]); }
  float wgt[8], sw = 0.0f;
  #pragma unroll
  for (int k = 0; k < 8; ++k) { wgt[k] = __expf(s[k] - m); sw += wgt[k]; }
  const float inv = 1.0f / sw;
  if (lane < 32) {
    float* wp = W8 + (p0w + pcol)*8;
    *(float4*)(wp)     = make_float4(wgt[0]*inv, wgt[1]*inv, wgt[2]*inv, wgt[3]*inv);
    *(float4*)(wp + 4) = make_float4(wgt[4]*inv, wgt[5]*inv, wgt[6]*inv, wgt[7]*inv);
  }
}

extern "C" void kernel_launch(void* const* d_in, const int* in_sizes, int n_in,
                              void* d_out, int out_size, void* d_ws, size_t ws_size,
                              hipStream_t stream) {
  const float* F_p      = (const float*)d_in[0];
  const float* proj_w   = (const float*)d_in[1];
  const float* proj_b   = (const float*)d_in[2];
  const float* refine_w = (const float*)d_in[3];
  const float* refine_b = (const float*)d_in[4];
  float* out = (float*)d_out;

  char* ws = (char*)d_ws;
  ushort* nbf    = (ushort*)ws;                                  // 64 MiB
  ushort* fbf    = (ushort*)(ws + (size_t)BPROWS*CC*2);          // 64 MiB
  float*  rnorm  = (float*)(ws + (size_t)BPROWS*CC*4);           // 512 KiB
  float*  centers= rnorm + BPROWS;                               // 64 KiB
  float*  accs   = centers + BB*NCLUS*CC;                        // 512 KiB
  float*  counts = accs + 8*BB*NCLUS*CC;                         // 256 B
  float*  CR     = counts + 64;                                  // 64 KiB
  ushort* cnormbf= (ushort*)(CR + BB*NCLUS*CC);                  // 32 KiB
  ushort* Wpb    = cnormbf + BB*NCLUS*CC;                        // 128 KiB
  ushort* Wrb    = Wpb + CC*CC;                                  // 128 KiB
  float*  W8     = (float*)(Wrb + CC*CC);                        // 4 MiB

  wcvt<<<64, 256, 0, stream>>>(proj_w, refine_w, Wpb, Wrb);
  gemm_bf16<true><<<1024, 512, 0, stream>>>(F_p, Wpb, proj_b, nbf, rnorm, nullptr, nullptr, fbf);
  centers_init<<<64, 256, 0, stream>>>(nbf, centers, cnormbf, accs, counts);
  for (int it = 0; it < 3; ++it) {
    assign_mfma<<<1024, 256, 0, stream>>>(nbf, cnormbf, accs, counts);
    centers_finalize<<<64, 256, 0, stream>>>(accs, counts, cnormbf, centers);
  }
  fuse_w8<<<1024, 256, 0, stream>>>(nbf, cnormbf, rnorm, W8);
  cr8_compute<<<64, 256, 0, stream>>>(centers, refine_w, CR);
  gemm_bf16<false><<<1024, 512, 0, stream>>>(fbf, Wrb, refine_b, out, nullptr, W8, CR, nullptr);
}